// Round 3
// baseline (454.160 us; speedup 1.0000x reference)
//
#include <hip/hip_runtime.h>
#include <hip/hip_bf16.h>
#include <stdint.h>
#include <stddef.h>

typedef _Float16 f16;
typedef __attribute__((ext_vector_type(8))) _Float16 f16x8;
typedef __attribute__((ext_vector_type(4))) _Float16 f16x4;
typedef __attribute__((ext_vector_type(4))) float f32x4;
typedef __attribute__((ext_vector_type(16))) float f32x16;

#define MFMA_F16(a, b, c) __builtin_amdgcn_mfma_f32_16x16x32_f16(a, b, c, 0, 0, 0)
#define MFMA32_F16(a, b, c) __builtin_amdgcn_mfma_f32_32x32x16_f16(a, b, c, 0, 0, 0)

#define LOG2_10K_32 0.41524101186092025f   // log2(10000)/32

__device__ __forceinline__ uint32_t swz(uint32_t ci) {
    return (ci & ~7u) | ((ci ^ (ci >> 3)) & 7u);
}

__device__ __forceinline__ void async_ld16(void* lds, const void* g) {
    __builtin_amdgcn_global_load_lds(
        (const __attribute__((address_space(1))) void*)g,
        (__attribute__((address_space(3))) void*)lds, 16, 0, 0);
}

// ---------------------------------------------------------------- transpose W
__global__ __launch_bounds__(256) void k_transpose_cast(
        const float* __restrict__ S, f16* __restrict__ D, int rows, int cols) {
    __shared__ float tile[32][33];
    int x = threadIdx.x & 31, y = threadIdx.x >> 5;
    int c0 = blockIdx.x * 32, r0 = blockIdx.y * 32;
#pragma unroll
    for (int i = 0; i < 32; i += 8)
        tile[y + i][x] = S[(size_t)(r0 + y + i) * cols + c0 + x];
    __syncthreads();
#pragma unroll
    for (int i = 0; i < 32; i += 8)
        D[(size_t)(c0 + y + i) * rows + r0 + x] = (f16)tile[x][y + i];
}

// ---------------------------------------------------------------- RMSNorm
__global__ __launch_bounds__(256) void k_rmsnorm(
        const float* __restrict__ seq, const float* __restrict__ w, f16* __restrict__ X) {
    int row = blockIdx.x, t = threadIdx.x;
    const float4* sp = (const float4*)(seq + (size_t)row * 1024);
    float4 v = sp[t];
    float ss = v.x * v.x + v.y * v.y + v.z * v.z + v.w * v.w;
#pragma unroll
    for (int off = 32; off >= 1; off >>= 1) ss += __shfl_xor(ss, off, 64);
    __shared__ float red[4];
    if ((t & 63) == 0) red[t >> 6] = ss;
    __syncthreads();
    float tot = red[0] + red[1] + red[2] + red[3];
    float rs = rsqrtf(tot * (1.0f / 1024.0f) + 1.1920929e-07f);
    const float4* wp = (const float4*)w;
    float4 wv = wp[t];
    f16x4 o;
    o[0] = (f16)(v.x * rs * wv.x);
    o[1] = (f16)(v.y * rs * wv.y);
    o[2] = (f16)(v.z * rs * wv.z);
    o[3] = (f16)(v.w * rs * wv.w);
    *(f16x4*)(X + (size_t)row * 1024 + t * 4) = o;
}

// ---------------------------------------------------------------- QKV GEMM (r5 structure: proven 158us)
__global__ __launch_bounds__(256) void k_gemm_qkv(
        const f16* __restrict__ A, const f16* __restrict__ BT,
        f16* __restrict__ Qb, f16* __restrict__ Kb, f16* __restrict__ Vt) {
    const int K = 1024;
    __shared__ f16 As[128 * 32];
    __shared__ f16 Bs[128 * 32];
    const int t = threadIdx.x;
    const int lane = t & 63, wave = t >> 6, l32 = lane & 31, half = lane >> 5;
    const int m0 = blockIdx.y * 128, n0 = blockIdx.x * 128;
    const int wm = (wave & 1) * 64, wn = (wave >> 1) * 64;
    f32x16 acc[2][2];
#pragma unroll
    for (int i = 0; i < 2; i++)
#pragma unroll
        for (int j = 0; j < 2; j++)
#pragma unroll
            for (int r = 0; r < 16; r++) acc[i][j][r] = 0.f;

    uint32_t aoff[2][2], boff[2][2];
#pragma unroll
    for (int bk = 0; bk < 2; bk++)
#pragma unroll
        for (int ks = 0; ks < 2; ks++) {
            aoff[bk][ks] = swz((uint32_t)(wm + bk * 32 + l32) * 4 + ks * 2 + half) * 16;
            boff[bk][ks] = swz((uint32_t)(wn + bk * 32 + l32) * 4 + ks * 2 + half) * 16;
        }
    uint32_t c0 = swz(t), c1 = swz(t + 256);
    const f16* Ag0 = A + (size_t)(m0 + (c0 >> 2)) * K + (c0 & 3) * 8;
    const f16* Ag1 = A + (size_t)(m0 + (c1 >> 2)) * K + (c1 & 3) * 8;
    const f16* Bg0 = BT + (size_t)(n0 + (c0 >> 2)) * K + (c0 & 3) * 8;
    const f16* Bg1 = BT + (size_t)(n0 + (c1 >> 2)) * K + (c1 & 3) * 8;
    char* AsB = (char*)As;
    char* BsB = (char*)Bs;

    for (int k0 = 0; k0 < K; k0 += 32) {
        __syncthreads();
        async_ld16(AsB + t * 16, Ag0 + k0);
        async_ld16(AsB + (t + 256) * 16, Ag1 + k0);
        async_ld16(BsB + t * 16, Bg0 + k0);
        async_ld16(BsB + (t + 256) * 16, Bg1 + k0);
        __builtin_amdgcn_s_waitcnt(0x0f70);  // vmcnt(0)
        __syncthreads();
        f16x8 a[2][2], b[2][2];
#pragma unroll
        for (int bk = 0; bk < 2; bk++)
#pragma unroll
            for (int ks = 0; ks < 2; ks++) {
                a[bk][ks] = *(const f16x8*)(AsB + aoff[bk][ks]);
                b[bk][ks] = *(const f16x8*)(BsB + boff[bk][ks]);
            }
#pragma unroll
        for (int mb = 0; mb < 2; mb++)
#pragma unroll
            for (int nb = 0; nb < 2; nb++) {
                acc[mb][nb] = MFMA32_F16(b[nb][0], a[mb][0], acc[mb][nb]);
                acc[mb][nb] = MFMA32_F16(b[nb][1], a[mb][1], acc[mb][nb]);
            }
    }

    // region uniform per block: 0=Q, 1=K, 2=V
    const int region = n0 >> 10;
#pragma unroll
    for (int mb = 0; mb < 2; mb++) {
        int row = m0 + wm + mb * 32 + l32;       // token 0..16383
        int b_ = row >> 13, n_ = row & 8191;
        int win = n_ >> 9, i_ = n_ & 511;
        float fn = (float)n_;
#pragma unroll
        for (int nb = 0; nb < 2; nb++) {
            int colb = n0 + wn + nb * 32 + half * 4;
            int cr = colb & 1023;                 // feature idx within region
            int h = cr >> 6;
            int d0 = cr & 63;                     // multiple of 4
            int wh = ((b_ * 16 + win) << 4) + h;
            if (region < 2) {
                f16* base = (region == 0)
                    ? (Qb + ((size_t)wh * 512 + i_) * 64)
                    : (Kb + ((size_t)wh * 576 + 16 + i_) * 64);
#pragma unroll
                for (int q = 0; q < 4; q++) {
                    int d = d0 + q * 8;
                    float j0f = (float)(d >> 1);
                    float ang0 = fn * exp2f(-LOG2_10K_32 * j0f);
                    float ang1 = fn * exp2f(-LOG2_10K_32 * (j0f + 1.0f));
                    float s0, c0f, s1, c1f;
                    sincosf(ang0, &s0, &c0f);
                    sincosf(ang1, &s1, &c1f);
                    float x0 = (float)(f16)acc[mb][nb][q * 4 + 0];
                    float x1 = (float)(f16)acc[mb][nb][q * 4 + 1];
                    float x2 = (float)(f16)acc[mb][nb][q * 4 + 2];
                    float x3 = (float)(f16)acc[mb][nb][q * 4 + 3];
                    f16x4 ov;
                    ov[0] = (f16)(x0 * c0f - x1 * s0);
                    ov[1] = (f16)(x1 * c0f + x0 * s0);
                    ov[2] = (f16)(x2 * c1f - x3 * s1);
                    ov[3] = (f16)(x3 * c1f + x2 * s1);
                    *(f16x4*)(base + d) = ov;
                }
            } else {
                f16* vbase = Vt + (size_t)wh * 36864 + 16 + i_;
#pragma unroll
                for (int q = 0; q < 4; q++)
#pragma unroll
                    for (int r = 0; r < 4; r++)
                        vbase[(size_t)(d0 + q * 8 + r) * 576] = (f16)acc[mb][nb][q * 4 + r];
            }
        }
    }
}

// ---------------------------------------------------------------- out GEMM (r5 structure)
__global__ __launch_bounds__(256) void k_gemm_out(
        const f16* __restrict__ A, const f16* __restrict__ BT,
        float* __restrict__ C, int M, int N, int K) {
    __shared__ f16 As[128 * 32];
    __shared__ f16 Bs[128 * 32];
    const int t = threadIdx.x;
    const int lane = t & 63, wave = t >> 6, l32 = lane & 31, half = lane >> 5;
    const int m0 = blockIdx.y * 128, n0 = blockIdx.x * 128;
    const int wm = (wave & 1) * 64, wn = (wave >> 1) * 64;
    f32x16 acc[2][2];
#pragma unroll
    for (int i = 0; i < 2; i++)
#pragma unroll
        for (int j = 0; j < 2; j++)
#pragma unroll
            for (int r = 0; r < 16; r++) acc[i][j][r] = 0.f;

    uint32_t aoff[2][2], boff[2][2];
#pragma unroll
    for (int bk = 0; bk < 2; bk++)
#pragma unroll
        for (int ks = 0; ks < 2; ks++) {
            aoff[bk][ks] = swz((uint32_t)(wm + bk * 32 + l32) * 4 + ks * 2 + half) * 16;
            boff[bk][ks] = swz((uint32_t)(wn + bk * 32 + l32) * 4 + ks * 2 + half) * 16;
        }
    uint32_t c0 = swz(t), c1 = swz(t + 256);
    const f16* Ag0 = A + (size_t)(m0 + (c0 >> 2)) * K + (c0 & 3) * 8;
    const f16* Ag1 = A + (size_t)(m0 + (c1 >> 2)) * K + (c1 & 3) * 8;
    const f16* Bg0 = BT + (size_t)(n0 + (c0 >> 2)) * K + (c0 & 3) * 8;
    const f16* Bg1 = BT + (size_t)(n0 + (c1 >> 2)) * K + (c1 & 3) * 8;
    char* AsB = (char*)As;
    char* BsB = (char*)Bs;

    for (int k0 = 0; k0 < K; k0 += 32) {
        __syncthreads();
        async_ld16(AsB + t * 16, Ag0 + k0);
        async_ld16(AsB + (t + 256) * 16, Ag1 + k0);
        async_ld16(BsB + t * 16, Bg0 + k0);
        async_ld16(BsB + (t + 256) * 16, Bg1 + k0);
        __builtin_amdgcn_s_waitcnt(0x0f70);  // vmcnt(0)
        __syncthreads();
        f16x8 a[2][2], b[2][2];
#pragma unroll
        for (int bk = 0; bk < 2; bk++)
#pragma unroll
            for (int ks = 0; ks < 2; ks++) {
                a[bk][ks] = *(const f16x8*)(AsB + aoff[bk][ks]);
                b[bk][ks] = *(const f16x8*)(BsB + boff[bk][ks]);
            }
#pragma unroll
        for (int mb = 0; mb < 2; mb++)
#pragma unroll
            for (int nb = 0; nb < 2; nb++) {
                acc[mb][nb] = MFMA32_F16(b[nb][0], a[mb][0], acc[mb][nb]);
                acc[mb][nb] = MFMA32_F16(b[nb][1], a[mb][1], acc[mb][nb]);
            }
    }
#pragma unroll
    for (int mb = 0; mb < 2; mb++) {
        int row = m0 + wm + mb * 32 + l32;
#pragma unroll
        for (int nb = 0; nb < 2; nb++) {
            int colb = n0 + wn + nb * 32 + half * 4;
#pragma unroll
            for (int q = 0; q < 4; q++) {
                f32x4 ov;
#pragma unroll
                for (int r = 0; r < 4; r++) ov[r] = acc[mb][nb][q * 4 + r];
                *(f32x4*)(C + (size_t)row * N + colb + q * 8) = ov;
            }
        }
    }
}

// ---------------------------------------------------------------- pm fill + pads
__global__ __launch_bounds__(256) void k_pmpad(
        const float* __restrict__ pm, f16* __restrict__ Kb, f16* __restrict__ Vt) {
    int wh = blockIdx.x, h = wh & 15, t = threadIdx.x;
    const float* pk = pm + (size_t)h * 1024;
    f16* kb = Kb + (size_t)wh * 36864;
    int e0 = t * 4;
#pragma unroll
    for (int k = 0; k < 4; k++) kb[e0 + k] = (f16)pk[e0 + k];
#pragma unroll
    for (int k = 0; k < 12; k++) kb[33792 + t + k * 256] = (f16)0.f;
    const float* pv = pm + 16384 + (size_t)h * 1024;
    f16* vb = Vt + (size_t)wh * 36864;
    {
        int d = t & 63, s4 = (t >> 6) * 4;
#pragma unroll
        for (int k = 0; k < 4; k++)
            vb[(size_t)d * 576 + s4 + k] = (f16)pv[(s4 + k) * 64 + d];
    }
    {
        int d = t >> 2, rep = t & 3;
#pragma unroll
        for (int m = 0; m < 12; m++)
            vb[(size_t)d * 576 + 528 + rep * 12 + m] = (f16)0.f;
    }
}

// ---------------------------------------------------------------- attention
// R8: double-buffered K/V prefetch (T14). Per tile: issue stage(jt+1) into
// the alternate buffer BEFORE computing tile jt; drain vmcnt(0) after PV.
// Barriers 3/tile -> 1/tile: the Ps round-trip is wave-local (Ps[wave][l16]
// written & read only by the same wave), so a wave-level lgkmcnt(0) suffices.
// Same ops, same order -> bit-identical output.
__global__ __launch_bounds__(256) void k_attn(
        const f16* __restrict__ Q, const f16* __restrict__ Kb,
        const f16* __restrict__ Vt, f16* __restrict__ AO) {
    const int qt = blockIdx.x, wh = blockIdx.y;
    const int i0 = qt * 64;
    const int t = threadIdx.x, lane = t & 63, wave = t >> 6, quad = lane >> 4, l16 = lane & 15;
    __shared__ f16 Ks[2][64 * 64];
    __shared__ f16 Vs[2][64 * 64];
    __shared__ f16 Ps[4][16][80];

    const int ig = i0 + wave * 16 + l16;
    const f16* qptr = Q + ((size_t)wh * 512 + ig) * 64 + quad * 8;
    f16x8 qf0 = *(const f16x8*)(qptr);
    f16x8 qf1 = *(const f16x8*)(qptr + 32);

    const f32x4 zero = {0.f, 0.f, 0.f, 0.f};
    f32x4 o[4];
#pragma unroll
    for (int i = 0; i < 4; i++) o[i] = zero;
    float m_l = -1e30f, l_l = 0.f;

    uint32_t c0 = swz(t), c1 = swz(t + 256);
    const f16* kg0 = Kb + ((size_t)wh * 576 + (c0 >> 3)) * 64 + (c0 & 7) * 8;
    const f16* kg1 = Kb + ((size_t)wh * 576 + (c1 >> 3)) * 64 + (c1 & 7) * 8;
    const f16* vg0 = Vt + ((size_t)wh * 64 + (c0 >> 3)) * 576 + (c0 & 7) * 8;
    const f16* vg1 = Vt + ((size_t)wh * 64 + (c1 >> 3)) * 576 + (c1 & 7) * 8;
    char* KsB = (char*)Ks;
    char* VsB = (char*)Vs;

    uint32_t boff[4][2];
#pragma unroll
    for (int i = 0; i < 4; i++)
#pragma unroll
        for (int f = 0; f < 2; f++)
            boff[i][f] = swz((uint32_t)(i * 16 + l16) * 8 + f * 4 + quad) * 16;

    f16* psrow = &Ps[wave][l16][0];
    const int njt = (qt + 2 < 9) ? (qt + 2) : 9;

    // prologue: stage tile 0 into buffer 0
    async_ld16(KsB + t * 16, kg0);
    async_ld16(KsB + (t + 256) * 16, kg1);
    async_ld16(VsB + t * 16, vg0);
    async_ld16(VsB + (t + 256) * 16, vg1);
    __builtin_amdgcn_s_waitcnt(0x0f70);  // vmcnt(0)
    __syncthreads();

    for (int jt = 0; jt < njt; jt++) {
        const int j0 = jt * 64;
        const uint32_t cb = (uint32_t)(jt & 1) * 8192;   // current buffer byte offset
        // prefetch next tile into the other buffer (its readers finished
        // before the barrier that ended iteration jt-1)
        if (jt + 1 < njt) {
            const uint32_t pb_ = 8192 - cb;
            const size_t j1 = (size_t)(j0 + 64);
            async_ld16(KsB + pb_ + t * 16, kg0 + j1 * 64);
            async_ld16(KsB + pb_ + (t + 256) * 16, kg1 + j1 * 64);
            async_ld16(VsB + pb_ + t * 16, vg0 + j1);
            async_ld16(VsB + pb_ + (t + 256) * 16, vg1 + j1);
        }

        f32x4 s[4];
#pragma unroll
        for (int jb = 0; jb < 4; jb++) {
            f16x8 kv0 = *(const f16x8*)(KsB + cb + boff[jb][0]);
            f16x8 kv1 = *(const f16x8*)(KsB + cb + boff[jb][1]);
            f32x4 z = zero;
            z = MFMA_F16(kv0, qf0, z);
            z = MFMA_F16(kv1, qf1, z);
            s[jb] = z;
        }
        float mx = -1e30f;
#pragma unroll
        for (int jb = 0; jb < 4; jb++)
#pragma unroll
            for (int r = 0; r < 4; r++) {
                int jg = j0 + jb * 16 + quad * 4 + r;
                bool ok = (jg <= ig + 16) && (jg < 528);
                float val = ok ? s[jb][r] * 0.125f : -1e30f;
                s[jb][r] = val;
                mx = fmaxf(mx, val);
            }
        mx = fmaxf(mx, __shfl_xor(mx, 16, 64));
        mx = fmaxf(mx, __shfl_xor(mx, 32, 64));
        float mnew = fmaxf(m_l, mx);
        float alpha = __expf(m_l - mnew);
        m_l = mnew;
        float rsum = 0.f;
#pragma unroll
        for (int jb = 0; jb < 4; jb++) {
            f16x4 pw;
#pragma unroll
            for (int r = 0; r < 4; r++) {
                float p = __expf(s[jb][r] - mnew);
                rsum += p;
                pw[r] = (f16)p;
            }
            *(f16x4*)(psrow + jb * 16 + quad * 4) = pw;
        }
        rsum += __shfl_xor(rsum, 16, 64);
        rsum += __shfl_xor(rsum, 32, 64);
        l_l = l_l * alpha + rsum;
#pragma unroll
        for (int nd = 0; nd < 4; nd++) o[nd] *= alpha;

        // Ps is wave-local: wave-level DS completion is enough (no barrier)
        __builtin_amdgcn_s_waitcnt(0xc07f);  // lgkmcnt(0)
        __builtin_amdgcn_sched_barrier(0);

        f16x8 pb0 = *(const f16x8*)(psrow + quad * 8);
        f16x8 pb1 = *(const f16x8*)(psrow + 32 + quad * 8);
#pragma unroll
        for (int nd = 0; nd < 4; nd++) {
            f16x8 v0 = *(const f16x8*)(VsB + cb + boff[nd][0]);
            f16x8 v1 = *(const f16x8*)(VsB + cb + boff[nd][1]);
            o[nd] = MFMA_F16(v0, pb0, o[nd]);
            o[nd] = MFMA_F16(v1, pb1, o[nd]);
        }

        __builtin_amdgcn_s_waitcnt(0x0f70);  // vmcnt(0): next tile landed
        __syncthreads();
    }

    const int bw = wh >> 4, h = wh & 15;
    float inv = 1.f / l_l;
    f16* dst = AO + ((size_t)bw * 512 + ig) * 1024 + h * 64 + quad * 4;
#pragma unroll
    for (int nd = 0; nd < 4; nd++) {
        f16x4 ov;
#pragma unroll
        for (int r = 0; r < 4; r++) ov[r] = (f16)(o[nd][r] * inv);
        *(f16x4*)(dst + nd * 16) = ov;
    }
}

// ---------------------------------------------------------------- launch
extern "C" void kernel_launch(void* const* d_in, const int* in_sizes, int n_in,
                              void* d_out, int out_size, void* d_ws, size_t ws_size,
                              hipStream_t stream) {
    const float* seq   = (const float*)d_in[0];
    const float* wnorm = (const float*)d_in[1];
    const float* Wqkv  = (const float*)d_in[2];
    const float* Wout  = (const float*)d_in[3];
    const float* pm    = (const float*)d_in[4];
    float* out = (float*)d_out;
    char* ws = (char*)d_ws;

    f16* WqkvT = (f16*)(ws + 0);            // 3072x1024  = 6 MB
    f16* WoutT = (f16*)(ws + 6291456);      // 1024x1024  = 2 MB
    f16* X     = (f16*)(ws + 8388608);      // 16384x1024 = 32 MB
    f16* Qb    = (f16*)(ws + 41943040);     // 512x512x64 = 32 MB
    f16* AO    = (f16*)(ws + 75497472);     // 16384x1024 = 32 MB
    f16* Kb    = (f16*)(ws + 109051904);    // 512x576x64 = 36 MB
    f16* Vt    = (f16*)(ws + 146800640);    // 512x64x576 = 36 MB  (end 176 MB)

    k_transpose_cast<<<dim3(96, 32), 256, 0, stream>>>(Wqkv, WqkvT, 1024, 3072);
    k_transpose_cast<<<dim3(32, 32), 256, 0, stream>>>(Wout, WoutT, 1024, 1024);
    k_rmsnorm<<<16384, 256, 0, stream>>>(seq, wnorm, X);
    k_pmpad<<<512, 256, 0, stream>>>(pm, Kb, Vt);
    k_gemm_qkv<<<dim3(24, 128), 256, 0, stream>>>(X, WqkvT, Qb, Kb, Vt);
    k_attn<<<dim3(8, 512), 256, 0, stream>>>(Qb, Kb, Vt, AO);
    k_gemm_out<<<dim3(8, 128), 256, 0, stream>>>(AO, WoutT, out, 16384, 1024, 1024);
}

// Round 4
// 422.215 us; speedup vs baseline: 1.0757x; 1.0757x over previous
//
#include <hip/hip_runtime.h>
#include <hip/hip_bf16.h>
#include <stdint.h>
#include <stddef.h>

typedef _Float16 f16;
typedef __attribute__((ext_vector_type(8))) _Float16 f16x8;
typedef __attribute__((ext_vector_type(4))) _Float16 f16x4;
typedef __attribute__((ext_vector_type(4))) float f32x4;
typedef __attribute__((ext_vector_type(16))) float f32x16;

#define MFMA_F16(a, b, c) __builtin_amdgcn_mfma_f32_16x16x32_f16(a, b, c, 0, 0, 0)
#define MFMA32_F16(a, b, c) __builtin_amdgcn_mfma_f32_32x32x16_f16(a, b, c, 0, 0, 0)

#define LOG2_10K_32 0.41524101186092025f   // log2(10000)/32

__device__ __forceinline__ uint32_t swz(uint32_t ci) {
    return (ci & ~7u) | ((ci ^ (ci >> 3)) & 7u);
}

__device__ __forceinline__ void async_ld16(void* lds, const void* g) {
    __builtin_amdgcn_global_load_lds(
        (const __attribute__((address_space(1))) void*)g,
        (__attribute__((address_space(3))) void*)lds, 16, 0, 0);
}

// ---------------------------------------------------------------- transpose W
__global__ __launch_bounds__(256) void k_transpose_cast(
        const float* __restrict__ S, f16* __restrict__ D, int rows, int cols) {
    __shared__ float tile[32][33];
    int x = threadIdx.x & 31, y = threadIdx.x >> 5;
    int c0 = blockIdx.x * 32, r0 = blockIdx.y * 32;
#pragma unroll
    for (int i = 0; i < 32; i += 8)
        tile[y + i][x] = S[(size_t)(r0 + y + i) * cols + c0 + x];
    __syncthreads();
#pragma unroll
    for (int i = 0; i < 32; i += 8)
        D[(size_t)(c0 + y + i) * rows + r0 + x] = (f16)tile[x][y + i];
}

// ---------------------------------------------------------------- RMSNorm
__global__ __launch_bounds__(256) void k_rmsnorm(
        const float* __restrict__ seq, const float* __restrict__ w, f16* __restrict__ X) {
    int row = blockIdx.x, t = threadIdx.x;
    const float4* sp = (const float4*)(seq + (size_t)row * 1024);
    float4 v = sp[t];
    float ss = v.x * v.x + v.y * v.y + v.z * v.z + v.w * v.w;
#pragma unroll
    for (int off = 32; off >= 1; off >>= 1) ss += __shfl_xor(ss, off, 64);
    __shared__ float red[4];
    if ((t & 63) == 0) red[t >> 6] = ss;
    __syncthreads();
    float tot = red[0] + red[1] + red[2] + red[3];
    float rs = rsqrtf(tot * (1.0f / 1024.0f) + 1.1920929e-07f);
    const float4* wp = (const float4*)w;
    float4 wv = wp[t];
    f16x4 o;
    o[0] = (f16)(v.x * rs * wv.x);
    o[1] = (f16)(v.y * rs * wv.y);
    o[2] = (f16)(v.z * rs * wv.z);
    o[3] = (f16)(v.w * rs * wv.w);
    *(f16x4*)(X + (size_t)row * 1024 + t * 4) = o;
}

// ---------------------------------------------------------------- QKV GEMM (r5 structure: proven 158us)
__global__ __launch_bounds__(256) void k_gemm_qkv(
        const f16* __restrict__ A, const f16* __restrict__ BT,
        f16* __restrict__ Qb, f16* __restrict__ Kb, f16* __restrict__ Vt) {
    const int K = 1024;
    __shared__ f16 As[128 * 32];
    __shared__ f16 Bs[128 * 32];
    const int t = threadIdx.x;
    const int lane = t & 63, wave = t >> 6, l32 = lane & 31, half = lane >> 5;
    const int m0 = blockIdx.y * 128, n0 = blockIdx.x * 128;
    const int wm = (wave & 1) * 64, wn = (wave >> 1) * 64;
    f32x16 acc[2][2];
#pragma unroll
    for (int i = 0; i < 2; i++)
#pragma unroll
        for (int j = 0; j < 2; j++)
#pragma unroll
            for (int r = 0; r < 16; r++) acc[i][j][r] = 0.f;

    uint32_t aoff[2][2], boff[2][2];
#pragma unroll
    for (int bk = 0; bk < 2; bk++)
#pragma unroll
        for (int ks = 0; ks < 2; ks++) {
            aoff[bk][ks] = swz((uint32_t)(wm + bk * 32 + l32) * 4 + ks * 2 + half) * 16;
            boff[bk][ks] = swz((uint32_t)(wn + bk * 32 + l32) * 4 + ks * 2 + half) * 16;
        }
    uint32_t c0 = swz(t), c1 = swz(t + 256);
    const f16* Ag0 = A + (size_t)(m0 + (c0 >> 2)) * K + (c0 & 3) * 8;
    const f16* Ag1 = A + (size_t)(m0 + (c1 >> 2)) * K + (c1 & 3) * 8;
    const f16* Bg0 = BT + (size_t)(n0 + (c0 >> 2)) * K + (c0 & 3) * 8;
    const f16* Bg1 = BT + (size_t)(n0 + (c1 >> 2)) * K + (c1 & 3) * 8;
    char* AsB = (char*)As;
    char* BsB = (char*)Bs;

    for (int k0 = 0; k0 < K; k0 += 32) {
        __syncthreads();
        async_ld16(AsB + t * 16, Ag0 + k0);
        async_ld16(AsB + (t + 256) * 16, Ag1 + k0);
        async_ld16(BsB + t * 16, Bg0 + k0);
        async_ld16(BsB + (t + 256) * 16, Bg1 + k0);
        __builtin_amdgcn_s_waitcnt(0x0f70);  // vmcnt(0)
        __syncthreads();
        f16x8 a[2][2], b[2][2];
#pragma unroll
        for (int bk = 0; bk < 2; bk++)
#pragma unroll
            for (int ks = 0; ks < 2; ks++) {
                a[bk][ks] = *(const f16x8*)(AsB + aoff[bk][ks]);
                b[bk][ks] = *(const f16x8*)(BsB + boff[bk][ks]);
            }
#pragma unroll
        for (int mb = 0; mb < 2; mb++)
#pragma unroll
            for (int nb = 0; nb < 2; nb++) {
                acc[mb][nb] = MFMA32_F16(b[nb][0], a[mb][0], acc[mb][nb]);
                acc[mb][nb] = MFMA32_F16(b[nb][1], a[mb][1], acc[mb][nb]);
            }
    }

    // region uniform per block: 0=Q, 1=K, 2=V
    const int region = n0 >> 10;
#pragma unroll
    for (int mb = 0; mb < 2; mb++) {
        int row = m0 + wm + mb * 32 + l32;       // token 0..16383
        int b_ = row >> 13, n_ = row & 8191;
        int win = n_ >> 9, i_ = n_ & 511;
        float fn = (float)n_;
#pragma unroll
        for (int nb = 0; nb < 2; nb++) {
            int colb = n0 + wn + nb * 32 + half * 4;
            int cr = colb & 1023;                 // feature idx within region
            int h = cr >> 6;
            int d0 = cr & 63;                     // multiple of 4
            int wh = ((b_ * 16 + win) << 4) + h;
            if (region < 2) {
                f16* base = (region == 0)
                    ? (Qb + ((size_t)wh * 512 + i_) * 64)
                    : (Kb + ((size_t)wh * 576 + 16 + i_) * 64);
#pragma unroll
                for (int q = 0; q < 4; q++) {
                    int d = d0 + q * 8;
                    float j0f = (float)(d >> 1);
                    float ang0 = fn * exp2f(-LOG2_10K_32 * j0f);
                    float ang1 = fn * exp2f(-LOG2_10K_32 * (j0f + 1.0f));
                    float s0, c0f, s1, c1f;
                    sincosf(ang0, &s0, &c0f);
                    sincosf(ang1, &s1, &c1f);
                    float x0 = (float)(f16)acc[mb][nb][q * 4 + 0];
                    float x1 = (float)(f16)acc[mb][nb][q * 4 + 1];
                    float x2 = (float)(f16)acc[mb][nb][q * 4 + 2];
                    float x3 = (float)(f16)acc[mb][nb][q * 4 + 3];
                    f16x4 ov;
                    ov[0] = (f16)(x0 * c0f - x1 * s0);
                    ov[1] = (f16)(x1 * c0f + x0 * s0);
                    ov[2] = (f16)(x2 * c1f - x3 * s1);
                    ov[3] = (f16)(x3 * c1f + x2 * s1);
                    *(f16x4*)(base + d) = ov;
                }
            } else {
                f16* vbase = Vt + (size_t)wh * 36864 + 16 + i_;
#pragma unroll
                for (int q = 0; q < 4; q++)
#pragma unroll
                    for (int r = 0; r < 4; r++)
                        vbase[(size_t)(d0 + q * 8 + r) * 576] = (f16)acc[mb][nb][q * 4 + r];
            }
        }
    }
}

// ---------------------------------------------------------------- out GEMM (r5 structure)
__global__ __launch_bounds__(256) void k_gemm_out(
        const f16* __restrict__ A, const f16* __restrict__ BT,
        float* __restrict__ C, int M, int N, int K) {
    __shared__ f16 As[128 * 32];
    __shared__ f16 Bs[128 * 32];
    const int t = threadIdx.x;
    const int lane = t & 63, wave = t >> 6, l32 = lane & 31, half = lane >> 5;
    const int m0 = blockIdx.y * 128, n0 = blockIdx.x * 128;
    const int wm = (wave & 1) * 64, wn = (wave >> 1) * 64;
    f32x16 acc[2][2];
#pragma unroll
    for (int i = 0; i < 2; i++)
#pragma unroll
        for (int j = 0; j < 2; j++)
#pragma unroll
            for (int r = 0; r < 16; r++) acc[i][j][r] = 0.f;

    uint32_t aoff[2][2], boff[2][2];
#pragma unroll
    for (int bk = 0; bk < 2; bk++)
#pragma unroll
        for (int ks = 0; ks < 2; ks++) {
            aoff[bk][ks] = swz((uint32_t)(wm + bk * 32 + l32) * 4 + ks * 2 + half) * 16;
            boff[bk][ks] = swz((uint32_t)(wn + bk * 32 + l32) * 4 + ks * 2 + half) * 16;
        }
    uint32_t c0 = swz(t), c1 = swz(t + 256);
    const f16* Ag0 = A + (size_t)(m0 + (c0 >> 2)) * K + (c0 & 3) * 8;
    const f16* Ag1 = A + (size_t)(m0 + (c1 >> 2)) * K + (c1 & 3) * 8;
    const f16* Bg0 = BT + (size_t)(n0 + (c0 >> 2)) * K + (c0 & 3) * 8;
    const f16* Bg1 = BT + (size_t)(n0 + (c1 >> 2)) * K + (c1 & 3) * 8;
    char* AsB = (char*)As;
    char* BsB = (char*)Bs;

    for (int k0 = 0; k0 < K; k0 += 32) {
        __syncthreads();
        async_ld16(AsB + t * 16, Ag0 + k0);
        async_ld16(AsB + (t + 256) * 16, Ag1 + k0);
        async_ld16(BsB + t * 16, Bg0 + k0);
        async_ld16(BsB + (t + 256) * 16, Bg1 + k0);
        __builtin_amdgcn_s_waitcnt(0x0f70);  // vmcnt(0)
        __syncthreads();
        f16x8 a[2][2], b[2][2];
#pragma unroll
        for (int bk = 0; bk < 2; bk++)
#pragma unroll
            for (int ks = 0; ks < 2; ks++) {
                a[bk][ks] = *(const f16x8*)(AsB + aoff[bk][ks]);
                b[bk][ks] = *(const f16x8*)(BsB + boff[bk][ks]);
            }
#pragma unroll
        for (int mb = 0; mb < 2; mb++)
#pragma unroll
            for (int nb = 0; nb < 2; nb++) {
                acc[mb][nb] = MFMA32_F16(b[nb][0], a[mb][0], acc[mb][nb]);
                acc[mb][nb] = MFMA32_F16(b[nb][1], a[mb][1], acc[mb][nb]);
            }
    }
#pragma unroll
    for (int mb = 0; mb < 2; mb++) {
        int row = m0 + wm + mb * 32 + l32;
#pragma unroll
        for (int nb = 0; nb < 2; nb++) {
            int colb = n0 + wn + nb * 32 + half * 4;
#pragma unroll
            for (int q = 0; q < 4; q++) {
                f32x4 ov;
#pragma unroll
                for (int r = 0; r < 4; r++) ov[r] = acc[mb][nb][q * 4 + r];
                *(f32x4*)(C + (size_t)row * N + colb + q * 8) = ov;
            }
        }
    }
}

// ---------------------------------------------------------------- pm fill + pads
__global__ __launch_bounds__(256) void k_pmpad(
        const float* __restrict__ pm, f16* __restrict__ Kb, f16* __restrict__ Vt) {
    int wh = blockIdx.x, h = wh & 15, t = threadIdx.x;
    const float* pk = pm + (size_t)h * 1024;
    f16* kb = Kb + (size_t)wh * 36864;
    int e0 = t * 4;
#pragma unroll
    for (int k = 0; k < 4; k++) kb[e0 + k] = (f16)pk[e0 + k];
#pragma unroll
    for (int k = 0; k < 12; k++) kb[33792 + t + k * 256] = (f16)0.f;
    const float* pv = pm + 16384 + (size_t)h * 1024;
    f16* vb = Vt + (size_t)wh * 36864;
    {
        int d = t & 63, s4 = (t >> 6) * 4;
#pragma unroll
        for (int k = 0; k < 4; k++)
            vb[(size_t)d * 576 + s4 + k] = (f16)pv[(s4 + k) * 64 + d];
    }
    {
        int d = t >> 2, rep = t & 3;
#pragma unroll
        for (int m = 0; m < 12; m++)
            vb[(size_t)d * 576 + 528 + rep * 12 + m] = (f16)0.f;
    }
}

// ---------------------------------------------------------------- attention
// R9: q-tile PAIR merge. One 512-thread / 8-wave block handles 128 q-rows
// (waves 0-7 -> 16 rows each), staging each K/V tile ONCE for 2x the
// compute of the old 256-thread block. Tile-stages 22528 -> 12288 (-45%).
// LDS 8K K + 8K V + 20K Ps = 36.9 KB -> 4 blocks x 8 waves = 32 waves/CU
// (vs baseline 24). 1D grid swizzled so the 4 pair-blocks sharing a wh
// land on the same XCD (bid%8 preserved) -> K/V L2-shared, HBM fetch ~once.
// Lower-half waves see extra fully-masked tiles: p=exp(-1e30-m)=0, alpha=1
// -> contribution exactly zero, absmax-identical output.
// Keeps R8-validated wave-local Ps sync (lgkmcnt instead of barrier).
__global__ __launch_bounds__(512) void k_attn(
        const f16* __restrict__ Q, const f16* __restrict__ Kb,
        const f16* __restrict__ Vt, f16* __restrict__ AO) {
    const int bid = blockIdx.x;
    const int wh = ((bid >> 5) << 3) | (bid & 7);   // bid = 32*(wh>>3) + 8*pair + (wh&7)
    const int pair = (bid >> 3) & 3;
    const int i0 = pair * 128;
    const int t = threadIdx.x, lane = t & 63, wave = t >> 6, quad = lane >> 4, l16 = lane & 15;
    __shared__ f16 Ks[64 * 64];
    __shared__ f16 Vs[64 * 64];
    __shared__ f16 Ps[8][16][80];

    const int ig = i0 + wave * 16 + l16;
    const f16* qptr = Q + ((size_t)wh * 512 + ig) * 64 + quad * 8;
    f16x8 qf0 = *(const f16x8*)(qptr);
    f16x8 qf1 = *(const f16x8*)(qptr + 32);

    const f32x4 zero = {0.f, 0.f, 0.f, 0.f};
    f32x4 o[4];
#pragma unroll
    for (int i = 0; i < 4; i++) o[i] = zero;
    float m_l = -1e30f, l_l = 0.f;

    uint32_t g = swz((uint32_t)t);                   // 512 granules, 1 load/thread
    const f16* kg0 = Kb + ((size_t)wh * 576 + (g >> 3)) * 64 + (g & 7) * 8;
    const f16* vg0 = Vt + ((size_t)wh * 64 + (g >> 3)) * 576 + (g & 7) * 8;
    char* KsB = (char*)Ks;
    char* VsB = (char*)Vs;

    uint32_t boff[4][2];
#pragma unroll
    for (int i = 0; i < 4; i++)
#pragma unroll
        for (int f = 0; f < 2; f++)
            boff[i][f] = swz((uint32_t)(i * 16 + l16) * 8 + f * 4 + quad) * 16;

    f16* psrow = &Ps[wave][l16][0];
    int njt = 2 * pair + 3;
    if (njt > 9) njt = 9;

    for (int jt = 0; jt < njt; jt++) {
        const int j0 = jt * 64;
        __syncthreads();                               // prev tile's PV reads done
        async_ld16(KsB + t * 16, kg0 + (size_t)j0 * 64);
        async_ld16(VsB + t * 16, vg0 + j0);
        __builtin_amdgcn_s_waitcnt(0x0f70);  // vmcnt(0)
        __syncthreads();

        f32x4 s[4];
#pragma unroll
        for (int jb = 0; jb < 4; jb++) {
            f16x8 kv0 = *(const f16x8*)(KsB + boff[jb][0]);
            f16x8 kv1 = *(const f16x8*)(KsB + boff[jb][1]);
            f32x4 z = zero;
            z = MFMA_F16(kv0, qf0, z);
            z = MFMA_F16(kv1, qf1, z);
            s[jb] = z;
        }
        float mx = -1e30f;
#pragma unroll
        for (int jb = 0; jb < 4; jb++)
#pragma unroll
            for (int r = 0; r < 4; r++) {
                int jg = j0 + jb * 16 + quad * 4 + r;
                bool ok = (jg <= ig + 16) && (jg < 528);
                float val = ok ? s[jb][r] * 0.125f : -1e30f;
                s[jb][r] = val;
                mx = fmaxf(mx, val);
            }
        mx = fmaxf(mx, __shfl_xor(mx, 16, 64));
        mx = fmaxf(mx, __shfl_xor(mx, 32, 64));
        float mnew = fmaxf(m_l, mx);
        float alpha = __expf(m_l - mnew);
        m_l = mnew;
        float rsum = 0.f;
#pragma unroll
        for (int jb = 0; jb < 4; jb++) {
            f16x4 pw;
#pragma unroll
            for (int r = 0; r < 4; r++) {
                float p = __expf(s[jb][r] - mnew);
                rsum += p;
                pw[r] = (f16)p;
            }
            *(f16x4*)(psrow + jb * 16 + quad * 4) = pw;
        }
        rsum += __shfl_xor(rsum, 16, 64);
        rsum += __shfl_xor(rsum, 32, 64);
        l_l = l_l * alpha + rsum;
#pragma unroll
        for (int nd = 0; nd < 4; nd++) o[nd] *= alpha;

        // Ps is wave-local: wave-level DS completion suffices (no barrier)
        __builtin_amdgcn_s_waitcnt(0xc07f);  // lgkmcnt(0)
        __builtin_amdgcn_sched_barrier(0);

        f16x8 pb0 = *(const f16x8*)(psrow + quad * 8);
        f16x8 pb1 = *(const f16x8*)(psrow + 32 + quad * 8);
#pragma unroll
        for (int nd = 0; nd < 4; nd++) {
            f16x8 v0 = *(const f16x8*)(VsB + boff[nd][0]);
            f16x8 v1 = *(const f16x8*)(VsB + boff[nd][1]);
            o[nd] = MFMA_F16(v0, pb0, o[nd]);
            o[nd] = MFMA_F16(v1, pb1, o[nd]);
        }
    }

    const int bw = wh >> 4, h = wh & 15;
    float inv = 1.f / l_l;
    f16* dst = AO + ((size_t)bw * 512 + ig) * 1024 + h * 64 + quad * 4;
#pragma unroll
    for (int nd = 0; nd < 4; nd++) {
        f16x4 ov;
#pragma unroll
        for (int r = 0; r < 4; r++) ov[r] = (f16)(o[nd][r] * inv);
        *(f16x4*)(dst + nd * 16) = ov;
    }
}

// ---------------------------------------------------------------- launch
extern "C" void kernel_launch(void* const* d_in, const int* in_sizes, int n_in,
                              void* d_out, int out_size, void* d_ws, size_t ws_size,
                              hipStream_t stream) {
    const float* seq   = (const float*)d_in[0];
    const float* wnorm = (const float*)d_in[1];
    const float* Wqkv  = (const float*)d_in[2];
    const float* Wout  = (const float*)d_in[3];
    const float* pm    = (const float*)d_in[4];
    float* out = (float*)d_out;
    char* ws = (char*)d_ws;

    f16* WqkvT = (f16*)(ws + 0);            // 3072x1024  = 6 MB
    f16* WoutT = (f16*)(ws + 6291456);      // 1024x1024  = 2 MB
    f16* X     = (f16*)(ws + 8388608);      // 16384x1024 = 32 MB
    f16* Qb    = (f16*)(ws + 41943040);     // 512x512x64 = 32 MB
    f16* AO    = (f16*)(ws + 75497472);     // 16384x1024 = 32 MB
    f16* Kb    = (f16*)(ws + 109051904);    // 512x576x64 = 36 MB
    f16* Vt    = (f16*)(ws + 146800640);    // 512x64x576 = 36 MB  (end 176 MB)

    k_transpose_cast<<<dim3(96, 32), 256, 0, stream>>>(Wqkv, WqkvT, 1024, 3072);
    k_transpose_cast<<<dim3(32, 32), 256, 0, stream>>>(Wout, WoutT, 1024, 1024);
    k_rmsnorm<<<16384, 256, 0, stream>>>(seq, wnorm, X);
    k_pmpad<<<512, 256, 0, stream>>>(pm, Kb, Vt);
    k_gemm_qkv<<<dim3(24, 128), 256, 0, stream>>>(X, WqkvT, Qb, Kb, Vt);
    k_attn<<<2048, 512, 0, stream>>>(Qb, Kb, Vt, AO);
    k_gemm_out<<<dim3(8, 128), 256, 0, stream>>>(AO, WoutT, out, 16384, 1024, 1024);
}

// Round 5
// 415.112 us; speedup vs baseline: 1.0941x; 1.0171x over previous
//
#include <hip/hip_runtime.h>
#include <hip/hip_bf16.h>
#include <stdint.h>
#include <stddef.h>

typedef _Float16 f16;
typedef __attribute__((ext_vector_type(8))) _Float16 f16x8;
typedef __attribute__((ext_vector_type(4))) _Float16 f16x4;
typedef __attribute__((ext_vector_type(4))) float f32x4;
typedef __attribute__((ext_vector_type(16))) float f32x16;

#define MFMA_F16(a, b, c) __builtin_amdgcn_mfma_f32_16x16x32_f16(a, b, c, 0, 0, 0)
#define MFMA32_F16(a, b, c) __builtin_amdgcn_mfma_f32_32x32x16_f16(a, b, c, 0, 0, 0)

#define LOG2_10K_32 0.41524101186092025f   // log2(10000)/32

__device__ __forceinline__ uint32_t swz(uint32_t ci) {
    return (ci & ~7u) | ((ci ^ (ci >> 3)) & 7u);
}

__device__ __forceinline__ void async_ld16(void* lds, const void* g) {
    __builtin_amdgcn_global_load_lds(
        (const __attribute__((address_space(1))) void*)g,
        (__attribute__((address_space(3))) void*)lds, 16, 0, 0);
}

// ---------------------------------------------------------------- transpose W
__global__ __launch_bounds__(256) void k_transpose_cast(
        const float* __restrict__ S, f16* __restrict__ D, int rows, int cols) {
    __shared__ float tile[32][33];
    int x = threadIdx.x & 31, y = threadIdx.x >> 5;
    int c0 = blockIdx.x * 32, r0 = blockIdx.y * 32;
#pragma unroll
    for (int i = 0; i < 32; i += 8)
        tile[y + i][x] = S[(size_t)(r0 + y + i) * cols + c0 + x];
    __syncthreads();
#pragma unroll
    for (int i = 0; i < 32; i += 8)
        D[(size_t)(c0 + y + i) * rows + r0 + x] = (f16)tile[x][y + i];
}

// ---------------------------------------------------------------- RMSNorm
__global__ __launch_bounds__(256) void k_rmsnorm(
        const float* __restrict__ seq, const float* __restrict__ w, f16* __restrict__ X) {
    int row = blockIdx.x, t = threadIdx.x;
    const float4* sp = (const float4*)(seq + (size_t)row * 1024);
    float4 v = sp[t];
    float ss = v.x * v.x + v.y * v.y + v.z * v.z + v.w * v.w;
#pragma unroll
    for (int off = 32; off >= 1; off >>= 1) ss += __shfl_xor(ss, off, 64);
    __shared__ float red[4];
    if ((t & 63) == 0) red[t >> 6] = ss;
    __syncthreads();
    float tot = red[0] + red[1] + red[2] + red[3];
    float rs = rsqrtf(tot * (1.0f / 1024.0f) + 1.1920929e-07f);
    const float4* wp = (const float4*)w;
    float4 wv = wp[t];
    f16x4 o;
    o[0] = (f16)(v.x * rs * wv.x);
    o[1] = (f16)(v.y * rs * wv.y);
    o[2] = (f16)(v.z * rs * wv.z);
    o[3] = (f16)(v.w * rs * wv.w);
    *(f16x4*)(X + (size_t)row * 1024 + t * 4) = o;
}

// ---------------------------------------------------------------- QKV GEMM (r5 structure: proven 158us)
__global__ __launch_bounds__(256) void k_gemm_qkv(
        const f16* __restrict__ A, const f16* __restrict__ BT,
        f16* __restrict__ Qb, f16* __restrict__ Kb, f16* __restrict__ Vt) {
    const int K = 1024;
    __shared__ f16 As[128 * 32];
    __shared__ f16 Bs[128 * 32];
    const int t = threadIdx.x;
    const int lane = t & 63, wave = t >> 6, l32 = lane & 31, half = lane >> 5;
    const int m0 = blockIdx.y * 128, n0 = blockIdx.x * 128;
    const int wm = (wave & 1) * 64, wn = (wave >> 1) * 64;
    f32x16 acc[2][2];
#pragma unroll
    for (int i = 0; i < 2; i++)
#pragma unroll
        for (int j = 0; j < 2; j++)
#pragma unroll
            for (int r = 0; r < 16; r++) acc[i][j][r] = 0.f;

    uint32_t aoff[2][2], boff[2][2];
#pragma unroll
    for (int bk = 0; bk < 2; bk++)
#pragma unroll
        for (int ks = 0; ks < 2; ks++) {
            aoff[bk][ks] = swz((uint32_t)(wm + bk * 32 + l32) * 4 + ks * 2 + half) * 16;
            boff[bk][ks] = swz((uint32_t)(wn + bk * 32 + l32) * 4 + ks * 2 + half) * 16;
        }
    uint32_t c0 = swz(t), c1 = swz(t + 256);
    const f16* Ag0 = A + (size_t)(m0 + (c0 >> 2)) * K + (c0 & 3) * 8;
    const f16* Ag1 = A + (size_t)(m0 + (c1 >> 2)) * K + (c1 & 3) * 8;
    const f16* Bg0 = BT + (size_t)(n0 + (c0 >> 2)) * K + (c0 & 3) * 8;
    const f16* Bg1 = BT + (size_t)(n0 + (c1 >> 2)) * K + (c1 & 3) * 8;
    char* AsB = (char*)As;
    char* BsB = (char*)Bs;

    for (int k0 = 0; k0 < K; k0 += 32) {
        __syncthreads();
        async_ld16(AsB + t * 16, Ag0 + k0);
        async_ld16(AsB + (t + 256) * 16, Ag1 + k0);
        async_ld16(BsB + t * 16, Bg0 + k0);
        async_ld16(BsB + (t + 256) * 16, Bg1 + k0);
        __builtin_amdgcn_s_waitcnt(0x0f70);  // vmcnt(0)
        __syncthreads();
        f16x8 a[2][2], b[2][2];
#pragma unroll
        for (int bk = 0; bk < 2; bk++)
#pragma unroll
            for (int ks = 0; ks < 2; ks++) {
                a[bk][ks] = *(const f16x8*)(AsB + aoff[bk][ks]);
                b[bk][ks] = *(const f16x8*)(BsB + boff[bk][ks]);
            }
#pragma unroll
        for (int mb = 0; mb < 2; mb++)
#pragma unroll
            for (int nb = 0; nb < 2; nb++) {
                acc[mb][nb] = MFMA32_F16(b[nb][0], a[mb][0], acc[mb][nb]);
                acc[mb][nb] = MFMA32_F16(b[nb][1], a[mb][1], acc[mb][nb]);
            }
    }

    // region uniform per block: 0=Q, 1=K, 2=V
    const int region = n0 >> 10;
#pragma unroll
    for (int mb = 0; mb < 2; mb++) {
        int row = m0 + wm + mb * 32 + l32;       // token 0..16383
        int b_ = row >> 13, n_ = row & 8191;
        int win = n_ >> 9, i_ = n_ & 511;
        float fn = (float)n_;
#pragma unroll
        for (int nb = 0; nb < 2; nb++) {
            int colb = n0 + wn + nb * 32 + half * 4;
            int cr = colb & 1023;                 // feature idx within region
            int h = cr >> 6;
            int d0 = cr & 63;                     // multiple of 4
            int wh = ((b_ * 16 + win) << 4) + h;
            if (region < 2) {
                f16* base = (region == 0)
                    ? (Qb + ((size_t)wh * 512 + i_) * 64)
                    : (Kb + ((size_t)wh * 576 + 16 + i_) * 64);
#pragma unroll
                for (int q = 0; q < 4; q++) {
                    int d = d0 + q * 8;
                    float j0f = (float)(d >> 1);
                    float ang0 = fn * exp2f(-LOG2_10K_32 * j0f);
                    float ang1 = fn * exp2f(-LOG2_10K_32 * (j0f + 1.0f));
                    float s0, c0f, s1, c1f;
                    sincosf(ang0, &s0, &c0f);
                    sincosf(ang1, &s1, &c1f);
                    float x0 = (float)(f16)acc[mb][nb][q * 4 + 0];
                    float x1 = (float)(f16)acc[mb][nb][q * 4 + 1];
                    float x2 = (float)(f16)acc[mb][nb][q * 4 + 2];
                    float x3 = (float)(f16)acc[mb][nb][q * 4 + 3];
                    f16x4 ov;
                    ov[0] = (f16)(x0 * c0f - x1 * s0);
                    ov[1] = (f16)(x1 * c0f + x0 * s0);
                    ov[2] = (f16)(x2 * c1f - x3 * s1);
                    ov[3] = (f16)(x3 * c1f + x2 * s1);
                    *(f16x4*)(base + d) = ov;
                }
            } else {
                f16* vbase = Vt + (size_t)wh * 36864 + 16 + i_;
#pragma unroll
                for (int q = 0; q < 4; q++)
#pragma unroll
                    for (int r = 0; r < 4; r++)
                        vbase[(size_t)(d0 + q * 8 + r) * 576] = (f16)acc[mb][nb][q * 4 + r];
            }
        }
    }
}

// ---------------------------------------------------------------- out GEMM (r5 structure)
__global__ __launch_bounds__(256) void k_gemm_out(
        const f16* __restrict__ A, const f16* __restrict__ BT,
        float* __restrict__ C, int M, int N, int K) {
    __shared__ f16 As[128 * 32];
    __shared__ f16 Bs[128 * 32];
    const int t = threadIdx.x;
    const int lane = t & 63, wave = t >> 6, l32 = lane & 31, half = lane >> 5;
    const int m0 = blockIdx.y * 128, n0 = blockIdx.x * 128;
    const int wm = (wave & 1) * 64, wn = (wave >> 1) * 64;
    f32x16 acc[2][2];
#pragma unroll
    for (int i = 0; i < 2; i++)
#pragma unroll
        for (int j = 0; j < 2; j++)
#pragma unroll
            for (int r = 0; r < 16; r++) acc[i][j][r] = 0.f;

    uint32_t aoff[2][2], boff[2][2];
#pragma unroll
    for (int bk = 0; bk < 2; bk++)
#pragma unroll
        for (int ks = 0; ks < 2; ks++) {
            aoff[bk][ks] = swz((uint32_t)(wm + bk * 32 + l32) * 4 + ks * 2 + half) * 16;
            boff[bk][ks] = swz((uint32_t)(wn + bk * 32 + l32) * 4 + ks * 2 + half) * 16;
        }
    uint32_t c0 = swz(t), c1 = swz(t + 256);
    const f16* Ag0 = A + (size_t)(m0 + (c0 >> 2)) * K + (c0 & 3) * 8;
    const f16* Ag1 = A + (size_t)(m0 + (c1 >> 2)) * K + (c1 & 3) * 8;
    const f16* Bg0 = BT + (size_t)(n0 + (c0 >> 2)) * K + (c0 & 3) * 8;
    const f16* Bg1 = BT + (size_t)(n0 + (c1 >> 2)) * K + (c1 & 3) * 8;
    char* AsB = (char*)As;
    char* BsB = (char*)Bs;

    for (int k0 = 0; k0 < K; k0 += 32) {
        __syncthreads();
        async_ld16(AsB + t * 16, Ag0 + k0);
        async_ld16(AsB + (t + 256) * 16, Ag1 + k0);
        async_ld16(BsB + t * 16, Bg0 + k0);
        async_ld16(BsB + (t + 256) * 16, Bg1 + k0);
        __builtin_amdgcn_s_waitcnt(0x0f70);  // vmcnt(0)
        __syncthreads();
        f16x8 a[2][2], b[2][2];
#pragma unroll
        for (int bk = 0; bk < 2; bk++)
#pragma unroll
            for (int ks = 0; ks < 2; ks++) {
                a[bk][ks] = *(const f16x8*)(AsB + aoff[bk][ks]);
                b[bk][ks] = *(const f16x8*)(BsB + boff[bk][ks]);
            }
#pragma unroll
        for (int mb = 0; mb < 2; mb++)
#pragma unroll
            for (int nb = 0; nb < 2; nb++) {
                acc[mb][nb] = MFMA32_F16(b[nb][0], a[mb][0], acc[mb][nb]);
                acc[mb][nb] = MFMA32_F16(b[nb][1], a[mb][1], acc[mb][nb]);
            }
    }
#pragma unroll
    for (int mb = 0; mb < 2; mb++) {
        int row = m0 + wm + mb * 32 + l32;
#pragma unroll
        for (int nb = 0; nb < 2; nb++) {
            int colb = n0 + wn + nb * 32 + half * 4;
#pragma unroll
            for (int q = 0; q < 4; q++) {
                f32x4 ov;
#pragma unroll
                for (int r = 0; r < 4; r++) ov[r] = acc[mb][nb][q * 4 + r];
                *(f32x4*)(C + (size_t)row * N + colb + q * 8) = ov;
            }
        }
    }
}

// ---------------------------------------------------------------- pm fill + pads
__global__ __launch_bounds__(256) void k_pmpad(
        const float* __restrict__ pm, f16* __restrict__ Kb, f16* __restrict__ Vt) {
    int wh = blockIdx.x, h = wh & 15, t = threadIdx.x;
    const float* pk = pm + (size_t)h * 1024;
    f16* kb = Kb + (size_t)wh * 36864;
    int e0 = t * 4;
#pragma unroll
    for (int k = 0; k < 4; k++) kb[e0 + k] = (f16)pk[e0 + k];
#pragma unroll
    for (int k = 0; k < 12; k++) kb[33792 + t + k * 256] = (f16)0.f;
    const float* pv = pm + 16384 + (size_t)h * 1024;
    f16* vb = Vt + (size_t)wh * 36864;
    {
        int d = t & 63, s4 = (t >> 6) * 4;
#pragma unroll
        for (int k = 0; k < 4; k++)
            vb[(size_t)d * 576 + s4 + k] = (f16)pv[(s4 + k) * 64 + d];
    }
    {
        int d = t >> 2, rep = t & 3;
#pragma unroll
        for (int m = 0; m < 12; m++)
            vb[(size_t)d * 576 + 528 + rep * 12 + m] = (f16)0.f;
    }
}

// ---------------------------------------------------------------- attention
// R10: T14 async-STAGE split on top of R9's pair-merge. Registers hold tile
// jt's K/V at loop top; after raw s_barrier (readers of jt-1 done) regs are
// ds_written to LDS and the loads for jt+1 are issued; compute of jt hides
// the HBM latency of jt+1. Raw barriers (NOT __syncthreads) so the compiler
// does not drain vmcnt across the barrier; lgkmcnt(0)+sched_barrier fences
// per guide rule #18. Same bytes, same arithmetic order -> bit-identical.
__global__ __launch_bounds__(512) void k_attn(
        const f16* __restrict__ Q, const f16* __restrict__ Kb,
        const f16* __restrict__ Vt, f16* __restrict__ AO) {
    const int bid = blockIdx.x;
    const int wh = ((bid >> 5) << 3) | (bid & 7);   // bid = 32*(wh>>3) + 8*pair + (wh&7)
    const int pair = (bid >> 3) & 3;
    const int i0 = pair * 128;
    const int t = threadIdx.x, lane = t & 63, wave = t >> 6, quad = lane >> 4, l16 = lane & 15;
    __shared__ f16 Ks[64 * 64];
    __shared__ f16 Vs[64 * 64];
    __shared__ f16 Ps[8][16][80];

    const int ig = i0 + wave * 16 + l16;
    const f16* qptr = Q + ((size_t)wh * 512 + ig) * 64 + quad * 8;
    f16x8 qf0 = *(const f16x8*)(qptr);
    f16x8 qf1 = *(const f16x8*)(qptr + 32);

    const f32x4 zero = {0.f, 0.f, 0.f, 0.f};
    f32x4 o[4];
#pragma unroll
    for (int i = 0; i < 4; i++) o[i] = zero;
    float m_l = -1e30f, l_l = 0.f;

    uint32_t g = swz((uint32_t)t);                   // 512 granules, 1 load/thread
    const f16* kg0 = Kb + ((size_t)wh * 576 + (g >> 3)) * 64 + (g & 7) * 8;
    const f16* vg0 = Vt + ((size_t)wh * 64 + (g >> 3)) * 576 + (g & 7) * 8;
    char* KsB = (char*)Ks;
    char* VsB = (char*)Vs;

    uint32_t boff[4][2];
#pragma unroll
    for (int i = 0; i < 4; i++)
#pragma unroll
        for (int f = 0; f < 2; f++)
            boff[i][f] = swz((uint32_t)(i * 16 + l16) * 8 + f * 4 + quad) * 16;

    f16* psrow = &Ps[wave][l16][0];
    int njt = 2 * pair + 3;
    if (njt > 9) njt = 9;

    // prologue: load tile 0 into regs (pre-swizzled global addr, linear LDS dest
    // later -> identical LDS layout to the global_load_lds path)
    f16x8 kreg = *(const f16x8*)(kg0);
    f16x8 vreg = *(const f16x8*)(vg0);

    for (int jt = 0; jt < njt; jt++) {
        const int j0 = jt * 64;
        // B1: all waves done reading LDS of tile jt-1 (raw barrier: no vmcnt drain)
        __builtin_amdgcn_sched_barrier(0);
        __builtin_amdgcn_s_barrier();
        __builtin_amdgcn_sched_barrier(0);
        // write tile jt regs -> LDS (compiler inserts the counted vmcnt for the
        // reg dependence; those loads completed during tile jt-1's compute)
        *(f16x8*)(KsB + t * 16) = kreg;
        *(f16x8*)(VsB + t * 16) = vreg;
        // issue tile jt+1 loads (overlap with this tile's compute)
        if (jt + 1 < njt) {
            kreg = *(const f16x8*)(kg0 + (size_t)(j0 + 64) * 64);
            vreg = *(const f16x8*)(vg0 + (j0 + 64));
        }
        // B2: this tile's LDS writes visible to all waves
        __builtin_amdgcn_s_waitcnt(0xc07f);  // lgkmcnt(0): own ds_writes done
        __builtin_amdgcn_sched_barrier(0);
        __builtin_amdgcn_s_barrier();
        __builtin_amdgcn_sched_barrier(0);

        f32x4 s[4];
#pragma unroll
        for (int jb = 0; jb < 4; jb++) {
            f16x8 kv0 = *(const f16x8*)(KsB + boff[jb][0]);
            f16x8 kv1 = *(const f16x8*)(KsB + boff[jb][1]);
            f32x4 z = zero;
            z = MFMA_F16(kv0, qf0, z);
            z = MFMA_F16(kv1, qf1, z);
            s[jb] = z;
        }
        float mx = -1e30f;
#pragma unroll
        for (int jb = 0; jb < 4; jb++)
#pragma unroll
            for (int r = 0; r < 4; r++) {
                int jg = j0 + jb * 16 + quad * 4 + r;
                bool ok = (jg <= ig + 16) && (jg < 528);
                float val = ok ? s[jb][r] * 0.125f : -1e30f;
                s[jb][r] = val;
                mx = fmaxf(mx, val);
            }
        mx = fmaxf(mx, __shfl_xor(mx, 16, 64));
        mx = fmaxf(mx, __shfl_xor(mx, 32, 64));
        float mnew = fmaxf(m_l, mx);
        float alpha = __expf(m_l - mnew);
        m_l = mnew;
        float rsum = 0.f;
#pragma unroll
        for (int jb = 0; jb < 4; jb++) {
            f16x4 pw;
#pragma unroll
            for (int r = 0; r < 4; r++) {
                float p = __expf(s[jb][r] - mnew);
                rsum += p;
                pw[r] = (f16)p;
            }
            *(f16x4*)(psrow + jb * 16 + quad * 4) = pw;
        }
        rsum += __shfl_xor(rsum, 16, 64);
        rsum += __shfl_xor(rsum, 32, 64);
        l_l = l_l * alpha + rsum;
#pragma unroll
        for (int nd = 0; nd < 4; nd++) o[nd] *= alpha;

        // Ps is wave-local: wave-level DS completion suffices (no barrier)
        __builtin_amdgcn_s_waitcnt(0xc07f);  // lgkmcnt(0)
        __builtin_amdgcn_sched_barrier(0);

        f16x8 pb0 = *(const f16x8*)(psrow + quad * 8);
        f16x8 pb1 = *(const f16x8*)(psrow + 32 + quad * 8);
#pragma unroll
        for (int nd = 0; nd < 4; nd++) {
            f16x8 v0 = *(const f16x8*)(VsB + boff[nd][0]);
            f16x8 v1 = *(const f16x8*)(VsB + boff[nd][1]);
            o[nd] = MFMA_F16(v0, pb0, o[nd]);
            o[nd] = MFMA_F16(v1, pb1, o[nd]);
        }
    }

    const int bw = wh >> 4, h = wh & 15;
    float inv = 1.f / l_l;
    f16* dst = AO + ((size_t)bw * 512 + ig) * 1024 + h * 64 + quad * 4;
#pragma unroll
    for (int nd = 0; nd < 4; nd++) {
        f16x4 ov;
#pragma unroll
        for (int r = 0; r < 4; r++) ov[r] = (f16)(o[nd][r] * inv);
        *(f16x4*)(dst + nd * 16) = ov;
    }
}

// ---------------------------------------------------------------- launch
extern "C" void kernel_launch(void* const* d_in, const int* in_sizes, int n_in,
                              void* d_out, int out_size, void* d_ws, size_t ws_size,
                              hipStream_t stream) {
    const float* seq   = (const float*)d_in[0];
    const float* wnorm = (const float*)d_in[1];
    const float* Wqkv  = (const float*)d_in[2];
    const float* Wout  = (const float*)d_in[3];
    const float* pm    = (const float*)d_in[4];
    float* out = (float*)d_out;
    char* ws = (char*)d_ws;

    f16* WqkvT = (f16*)(ws + 0);            // 3072x1024  = 6 MB
    f16* WoutT = (f16*)(ws + 6291456);      // 1024x1024  = 2 MB
    f16* X     = (f16*)(ws + 8388608);      // 16384x1024 = 32 MB
    f16* Qb    = (f16*)(ws + 41943040);     // 512x512x64 = 32 MB
    f16* AO    = (f16*)(ws + 75497472);     // 16384x1024 = 32 MB
    f16* Kb    = (f16*)(ws + 109051904);    // 512x576x64 = 36 MB
    f16* Vt    = (f16*)(ws + 146800640);    // 512x64x576 = 36 MB  (end 176 MB)

    k_transpose_cast<<<dim3(96, 32), 256, 0, stream>>>(Wqkv, WqkvT, 1024, 3072);
    k_transpose_cast<<<dim3(32, 32), 256, 0, stream>>>(Wout, WoutT, 1024, 1024);
    k_rmsnorm<<<16384, 256, 0, stream>>>(seq, wnorm, X);
    k_pmpad<<<512, 256, 0, stream>>>(pm, Kb, Vt);
    k_gemm_qkv<<<dim3(24, 128), 256, 0, stream>>>(X, WqkvT, Qb, Kb, Vt);
    k_attn<<<2048, 512, 0, stream>>>(Qb, Kb, Vt, AO);
    k_gemm_out<<<dim3(8, 128), 256, 0, stream>>>(AO, WoutT, out, 16384, 1024, 1024);
}

// Round 7
// 407.442 us; speedup vs baseline: 1.1147x; 1.0188x over previous
//
#include <hip/hip_runtime.h>
#include <hip/hip_bf16.h>
#include <stdint.h>
#include <stddef.h>

typedef _Float16 f16;
typedef __attribute__((ext_vector_type(8))) _Float16 f16x8;
typedef __attribute__((ext_vector_type(4))) _Float16 f16x4;
typedef __attribute__((ext_vector_type(4))) float f32x4;
typedef __attribute__((ext_vector_type(16))) float f32x16;

#define MFMA_F16(a, b, c) __builtin_amdgcn_mfma_f32_16x16x32_f16(a, b, c, 0, 0, 0)
#define MFMA32_F16(a, b, c) __builtin_amdgcn_mfma_f32_32x32x16_f16(a, b, c, 0, 0, 0)

#define LOG2_10K_32 0.41524101186092025f   // log2(10000)/32

__device__ __forceinline__ uint32_t swz(uint32_t ci) {
    return (ci & ~7u) | ((ci ^ (ci >> 3)) & 7u);
}

__device__ __forceinline__ void async_ld16(void* lds, const void* g) {
    __builtin_amdgcn_global_load_lds(
        (const __attribute__((address_space(1))) void*)g,
        (__attribute__((address_space(3))) void*)lds, 16, 0, 0);
}

// ---------------------------------------------------------------- transpose W
__global__ __launch_bounds__(256) void k_transpose_cast(
        const float* __restrict__ S, f16* __restrict__ D, int rows, int cols) {
    __shared__ float tile[32][33];
    int x = threadIdx.x & 31, y = threadIdx.x >> 5;
    int c0 = blockIdx.x * 32, r0 = blockIdx.y * 32;
#pragma unroll
    for (int i = 0; i < 32; i += 8)
        tile[y + i][x] = S[(size_t)(r0 + y + i) * cols + c0 + x];
    __syncthreads();
#pragma unroll
    for (int i = 0; i < 32; i += 8)
        D[(size_t)(c0 + y + i) * rows + r0 + x] = (f16)tile[x][y + i];
}

// ---------------------------------------------------------------- RMSNorm
__global__ __launch_bounds__(256) void k_rmsnorm(
        const float* __restrict__ seq, const float* __restrict__ w, f16* __restrict__ X) {
    int row = blockIdx.x, t = threadIdx.x;
    const float4* sp = (const float4*)(seq + (size_t)row * 1024);
    float4 v = sp[t];
    float ss = v.x * v.x + v.y * v.y + v.z * v.z + v.w * v.w;
#pragma unroll
    for (int off = 32; off >= 1; off >>= 1) ss += __shfl_xor(ss, off, 64);
    __shared__ float red[4];
    if ((t & 63) == 0) red[t >> 6] = ss;
    __syncthreads();
    float tot = red[0] + red[1] + red[2] + red[3];
    float rs = rsqrtf(tot * (1.0f / 1024.0f) + 1.1920929e-07f);
    const float4* wp = (const float4*)w;
    float4 wv = wp[t];
    f16x4 o;
    o[0] = (f16)(v.x * rs * wv.x);
    o[1] = (f16)(v.y * rs * wv.y);
    o[2] = (f16)(v.z * rs * wv.z);
    o[3] = (f16)(v.w * rs * wv.w);
    *(f16x4*)(X + (size_t)row * 1024 + t * 4) = o;
}

// ---------------------------------------------------------------- QKV GEMM (r5 structure: proven 158us)
__global__ __launch_bounds__(256) void k_gemm_qkv(
        const f16* __restrict__ A, const f16* __restrict__ BT,
        f16* __restrict__ Qb, f16* __restrict__ Kb, f16* __restrict__ Vt) {
    const int K = 1024;
    __shared__ f16 As[128 * 32];
    __shared__ f16 Bs[128 * 32];
    const int t = threadIdx.x;
    const int lane = t & 63, wave = t >> 6, l32 = lane & 31, half = lane >> 5;
    const int m0 = blockIdx.y * 128, n0 = blockIdx.x * 128;
    const int wm = (wave & 1) * 64, wn = (wave >> 1) * 64;
    f32x16 acc[2][2];
#pragma unroll
    for (int i = 0; i < 2; i++)
#pragma unroll
        for (int j = 0; j < 2; j++)
#pragma unroll
            for (int r = 0; r < 16; r++) acc[i][j][r] = 0.f;

    uint32_t aoff[2][2], boff[2][2];
#pragma unroll
    for (int bk = 0; bk < 2; bk++)
#pragma unroll
        for (int ks = 0; ks < 2; ks++) {
            aoff[bk][ks] = swz((uint32_t)(wm + bk * 32 + l32) * 4 + ks * 2 + half) * 16;
            boff[bk][ks] = swz((uint32_t)(wn + bk * 32 + l32) * 4 + ks * 2 + half) * 16;
        }
    uint32_t c0 = swz(t), c1 = swz(t + 256);
    const f16* Ag0 = A + (size_t)(m0 + (c0 >> 2)) * K + (c0 & 3) * 8;
    const f16* Ag1 = A + (size_t)(m0 + (c1 >> 2)) * K + (c1 & 3) * 8;
    const f16* Bg0 = BT + (size_t)(n0 + (c0 >> 2)) * K + (c0 & 3) * 8;
    const f16* Bg1 = BT + (size_t)(n0 + (c1 >> 2)) * K + (c1 & 3) * 8;
    char* AsB = (char*)As;
    char* BsB = (char*)Bs;

    for (int k0 = 0; k0 < K; k0 += 32) {
        __syncthreads();
        async_ld16(AsB + t * 16, Ag0 + k0);
        async_ld16(AsB + (t + 256) * 16, Ag1 + k0);
        async_ld16(BsB + t * 16, Bg0 + k0);
        async_ld16(BsB + (t + 256) * 16, Bg1 + k0);
        __builtin_amdgcn_s_waitcnt(0x0f70);  // vmcnt(0)
        __syncthreads();
        f16x8 a[2][2], b[2][2];
#pragma unroll
        for (int bk = 0; bk < 2; bk++)
#pragma unroll
            for (int ks = 0; ks < 2; ks++) {
                a[bk][ks] = *(const f16x8*)(AsB + aoff[bk][ks]);
                b[bk][ks] = *(const f16x8*)(BsB + boff[bk][ks]);
            }
#pragma unroll
        for (int mb = 0; mb < 2; mb++)
#pragma unroll
            for (int nb = 0; nb < 2; nb++) {
                acc[mb][nb] = MFMA32_F16(b[nb][0], a[mb][0], acc[mb][nb]);
                acc[mb][nb] = MFMA32_F16(b[nb][1], a[mb][1], acc[mb][nb]);
            }
    }

    // region uniform per block: 0=Q, 1=K, 2=V
    const int region = n0 >> 10;
#pragma unroll
    for (int mb = 0; mb < 2; mb++) {
        int row = m0 + wm + mb * 32 + l32;       // token 0..16383
        int b_ = row >> 13, n_ = row & 8191;
        int win = n_ >> 9, i_ = n_ & 511;
        float fn = (float)n_;
#pragma unroll
        for (int nb = 0; nb < 2; nb++) {
            int colb = n0 + wn + nb * 32 + half * 4;
            int cr = colb & 1023;                 // feature idx within region
            int h = cr >> 6;
            int d0 = cr & 63;                     // multiple of 4
            int wh = ((b_ * 16 + win) << 4) + h;
            if (region < 2) {
                f16* base = (region == 0)
                    ? (Qb + ((size_t)wh * 512 + i_) * 64)
                    : (Kb + ((size_t)wh * 576 + 16 + i_) * 64);
#pragma unroll
                for (int q = 0; q < 4; q++) {
                    int d = d0 + q * 8;
                    float j0f = (float)(d >> 1);
                    float ang0 = fn * exp2f(-LOG2_10K_32 * j0f);
                    float ang1 = fn * exp2f(-LOG2_10K_32 * (j0f + 1.0f));
                    float s0, c0f, s1, c1f;
                    sincosf(ang0, &s0, &c0f);
                    sincosf(ang1, &s1, &c1f);
                    float x0 = (float)(f16)acc[mb][nb][q * 4 + 0];
                    float x1 = (float)(f16)acc[mb][nb][q * 4 + 1];
                    float x2 = (float)(f16)acc[mb][nb][q * 4 + 2];
                    float x3 = (float)(f16)acc[mb][nb][q * 4 + 3];
                    f16x4 ov;
                    ov[0] = (f16)(x0 * c0f - x1 * s0);
                    ov[1] = (f16)(x1 * c0f + x0 * s0);
                    ov[2] = (f16)(x2 * c1f - x3 * s1);
                    ov[3] = (f16)(x3 * c1f + x2 * s1);
                    *(f16x4*)(base + d) = ov;
                }
            } else {
                f16* vbase = Vt + (size_t)wh * 36864 + 16 + i_;
#pragma unroll
                for (int q = 0; q < 4; q++)
#pragma unroll
                    for (int r = 0; r < 4; r++)
                        vbase[(size_t)(d0 + q * 8 + r) * 576] = (f16)acc[mb][nb][q * 4 + r];
            }
        }
    }
}

// ---------------------------------------------------------------- out GEMM (r5 structure)
__global__ __launch_bounds__(256) void k_gemm_out(
        const f16* __restrict__ A, const f16* __restrict__ BT,
        float* __restrict__ C, int M, int N, int K) {
    __shared__ f16 As[128 * 32];
    __shared__ f16 Bs[128 * 32];
    const int t = threadIdx.x;
    const int lane = t & 63, wave = t >> 6, l32 = lane & 31, half = lane >> 5;
    const int m0 = blockIdx.y * 128, n0 = blockIdx.x * 128;
    const int wm = (wave & 1) * 64, wn = (wave >> 1) * 64;
    f32x16 acc[2][2];
#pragma unroll
    for (int i = 0; i < 2; i++)
#pragma unroll
        for (int j = 0; j < 2; j++)
#pragma unroll
            for (int r = 0; r < 16; r++) acc[i][j][r] = 0.f;

    uint32_t aoff[2][2], boff[2][2];
#pragma unroll
    for (int bk = 0; bk < 2; bk++)
#pragma unroll
        for (int ks = 0; ks < 2; ks++) {
            aoff[bk][ks] = swz((uint32_t)(wm + bk * 32 + l32) * 4 + ks * 2 + half) * 16;
            boff[bk][ks] = swz((uint32_t)(wn + bk * 32 + l32) * 4 + ks * 2 + half) * 16;
        }
    uint32_t c0 = swz(t), c1 = swz(t + 256);
    const f16* Ag0 = A + (size_t)(m0 + (c0 >> 2)) * K + (c0 & 3) * 8;
    const f16* Ag1 = A + (size_t)(m0 + (c1 >> 2)) * K + (c1 & 3) * 8;
    const f16* Bg0 = BT + (size_t)(n0 + (c0 >> 2)) * K + (c0 & 3) * 8;
    const f16* Bg1 = BT + (size_t)(n0 + (c1 >> 2)) * K + (c1 & 3) * 8;
    char* AsB = (char*)As;
    char* BsB = (char*)Bs;

    for (int k0 = 0; k0 < K; k0 += 32) {
        __syncthreads();
        async_ld16(AsB + t * 16, Ag0 + k0);
        async_ld16(AsB + (t + 256) * 16, Ag1 + k0);
        async_ld16(BsB + t * 16, Bg0 + k0);
        async_ld16(BsB + (t + 256) * 16, Bg1 + k0);
        __builtin_amdgcn_s_waitcnt(0x0f70);  // vmcnt(0)
        __syncthreads();
        f16x8 a[2][2], b[2][2];
#pragma unroll
        for (int bk = 0; bk < 2; bk++)
#pragma unroll
            for (int ks = 0; ks < 2; ks++) {
                a[bk][ks] = *(const f16x8*)(AsB + aoff[bk][ks]);
                b[bk][ks] = *(const f16x8*)(BsB + boff[bk][ks]);
            }
#pragma unroll
        for (int mb = 0; mb < 2; mb++)
#pragma unroll
            for (int nb = 0; nb < 2; nb++) {
                acc[mb][nb] = MFMA32_F16(b[nb][0], a[mb][0], acc[mb][nb]);
                acc[mb][nb] = MFMA32_F16(b[nb][1], a[mb][1], acc[mb][nb]);
            }
    }
#pragma unroll
    for (int mb = 0; mb < 2; mb++) {
        int row = m0 + wm + mb * 32 + l32;
#pragma unroll
        for (int nb = 0; nb < 2; nb++) {
            int colb = n0 + wn + nb * 32 + half * 4;
#pragma unroll
            for (int q = 0; q < 4; q++) {
                f32x4 ov;
#pragma unroll
                for (int r = 0; r < 4; r++) ov[r] = acc[mb][nb][q * 4 + r];
                *(f32x4*)(C + (size_t)row * N + colb + q * 8) = ov;
            }
        }
    }
}

// ---------------------------------------------------------------- pm fill + pads
__global__ __launch_bounds__(256) void k_pmpad(
        const float* __restrict__ pm, f16* __restrict__ Kb, f16* __restrict__ Vt) {
    int wh = blockIdx.x, h = wh & 15, t = threadIdx.x;
    const float* pk = pm + (size_t)h * 1024;
    f16* kb = Kb + (size_t)wh * 36864;
    int e0 = t * 4;
#pragma unroll
    for (int k = 0; k < 4; k++) kb[e0 + k] = (f16)pk[e0 + k];
#pragma unroll
    for (int k = 0; k < 12; k++) kb[33792 + t + k * 256] = (f16)0.f;
    const float* pv = pm + 16384 + (size_t)h * 1024;
    f16* vb = Vt + (size_t)wh * 36864;
    {
        int d = t & 63, s4 = (t >> 6) * 4;
#pragma unroll
        for (int k = 0; k < 4; k++)
            vb[(size_t)d * 576 + s4 + k] = (f16)pv[(s4 + k) * 64 + d];
    }
    {
        int d = t >> 2, rep = t & 3;
#pragma unroll
        for (int m = 0; m < 12; m++)
            vb[(size_t)d * 576 + 528 + rep * 12 + m] = (f16)0.f;
    }
}

// ---------------------------------------------------------------- attention
// R11 (resubmit; prior round was an infra failure, kernel never measured)
// = R10 (pair-merge + async reg-stage) + bit-exact softmax VALU trim:
//  (a) interior-tile fast path: wave-uniform "fully unmasked" test removes
//      the 16-deep cmp/cmp/cndmask chain on ~70% of tiles;
//      boundary tiles fold 2 compares into one via jcap = min(ig+16, 527).
//  (b) skip-rescale when __all(mx <= m_l): then mnew==m_l bitwise and
//      alpha = exp(0) = 1.0f exactly, so o*=alpha / l_l*alpha+rsum are
//      identity ops -> skip them wave-uniformly. Both are bit-identical
//      transformations (absmax must stay exactly 0.00390625).
__global__ __launch_bounds__(512) void k_attn(
        const f16* __restrict__ Q, const f16* __restrict__ Kb,
        const f16* __restrict__ Vt, f16* __restrict__ AO) {
    const int bid = blockIdx.x;
    const int wh = ((bid >> 5) << 3) | (bid & 7);   // bid = 32*(wh>>3) + 8*pair + (wh&7)
    const int pair = (bid >> 3) & 3;
    const int i0 = pair * 128;
    const int t = threadIdx.x, lane = t & 63, wave = t >> 6, quad = lane >> 4, l16 = lane & 15;
    __shared__ f16 Ks[64 * 64];
    __shared__ f16 Vs[64 * 64];
    __shared__ f16 Ps[8][16][80];

    const int ig = i0 + wave * 16 + l16;
    const f16* qptr = Q + ((size_t)wh * 512 + ig) * 64 + quad * 8;
    f16x8 qf0 = *(const f16x8*)(qptr);
    f16x8 qf1 = *(const f16x8*)(qptr + 32);

    const f32x4 zero = {0.f, 0.f, 0.f, 0.f};
    f32x4 o[4];
#pragma unroll
    for (int i = 0; i < 4; i++) o[i] = zero;
    float m_l = -1e30f, l_l = 0.f;

    uint32_t g = swz((uint32_t)t);                   // 512 granules, 1 load/thread
    const f16* kg0 = Kb + ((size_t)wh * 576 + (g >> 3)) * 64 + (g & 7) * 8;
    const f16* vg0 = Vt + ((size_t)wh * 64 + (g >> 3)) * 576 + (g & 7) * 8;
    char* KsB = (char*)Ks;
    char* VsB = (char*)Vs;

    uint32_t boff[4][2];
#pragma unroll
    for (int i = 0; i < 4; i++)
#pragma unroll
        for (int f = 0; f < 2; f++)
            boff[i][f] = swz((uint32_t)(i * 16 + l16) * 8 + f * 4 + quad) * 16;

    f16* psrow = &Ps[wave][l16][0];
    int njt = 2 * pair + 3;
    if (njt > 9) njt = 9;

    const int jcap = (ig + 16 < 527) ? (ig + 16) : 527;   // jg<=ig+16 && jg<528

    // prologue: load tile 0 into regs (pre-swizzled global addr, linear LDS dest)
    f16x8 kreg = *(const f16x8*)(kg0);
    f16x8 vreg = *(const f16x8*)(vg0);

    for (int jt = 0; jt < njt; jt++) {
        const int j0 = jt * 64;
        // B1: all waves done reading LDS of tile jt-1 (raw barrier: no vmcnt drain)
        __builtin_amdgcn_sched_barrier(0);
        __builtin_amdgcn_s_barrier();
        __builtin_amdgcn_sched_barrier(0);
        *(f16x8*)(KsB + t * 16) = kreg;
        *(f16x8*)(VsB + t * 16) = vreg;
        if (jt + 1 < njt) {
            kreg = *(const f16x8*)(kg0 + (size_t)(j0 + 64) * 64);
            vreg = *(const f16x8*)(vg0 + (j0 + 64));
        }
        // B2: this tile's LDS writes visible to all waves
        __builtin_amdgcn_s_waitcnt(0xc07f);  // lgkmcnt(0): own ds_writes done
        __builtin_amdgcn_sched_barrier(0);
        __builtin_amdgcn_s_barrier();
        __builtin_amdgcn_sched_barrier(0);

        f32x4 s[4];
#pragma unroll
        for (int jb = 0; jb < 4; jb++) {
            f16x8 kv0 = *(const f16x8*)(KsB + boff[jb][0]);
            f16x8 kv1 = *(const f16x8*)(KsB + boff[jb][1]);
            f32x4 z = zero;
            z = MFMA_F16(kv0, qf0, z);
            z = MFMA_F16(kv1, qf1, z);
            s[jb] = z;
        }

        // wave-uniform: tile fully unmasked for every lane of this wave?
        const bool fullt = (j0 + 63 <= i0 + wave * 16 + 16) && (j0 + 64 <= 528);
        float mx = -1e30f;
        if (fullt) {
#pragma unroll
            for (int jb = 0; jb < 4; jb++)
#pragma unroll
                for (int r = 0; r < 4; r++) {
                    float val = s[jb][r] * 0.125f;
                    s[jb][r] = val;
                    mx = fmaxf(mx, val);
                }
        } else {
#pragma unroll
            for (int jb = 0; jb < 4; jb++)
#pragma unroll
                for (int r = 0; r < 4; r++) {
                    int jg = j0 + jb * 16 + quad * 4 + r;
                    float val = (jg <= jcap) ? s[jb][r] * 0.125f : -1e30f;
                    s[jb][r] = val;
                    mx = fmaxf(mx, val);
                }
        }
        mx = fmaxf(mx, __shfl_xor(mx, 16, 64));
        mx = fmaxf(mx, __shfl_xor(mx, 32, 64));
        const bool skipresc = __all(mx <= m_l);        // -> mnew==m_l, alpha==1 exactly
        float mnew = fmaxf(m_l, mx);
        float alpha = 1.0f;
        if (!skipresc) alpha = __expf(m_l - mnew);
        m_l = mnew;
        float rsum = 0.f;
#pragma unroll
        for (int jb = 0; jb < 4; jb++) {
            f16x4 pw;
#pragma unroll
            for (int r = 0; r < 4; r++) {
                float p = __expf(s[jb][r] - mnew);
                rsum += p;
                pw[r] = (f16)p;
            }
            *(f16x4*)(psrow + jb * 16 + quad * 4) = pw;
        }
        rsum += __shfl_xor(rsum, 16, 64);
        rsum += __shfl_xor(rsum, 32, 64);
        if (skipresc) {
            l_l = l_l + rsum;                          // == l_l*1.0f + rsum bitwise
        } else {
            l_l = l_l * alpha + rsum;
#pragma unroll
            for (int nd = 0; nd < 4; nd++) o[nd] *= alpha;
        }

        // Ps is wave-local: wave-level DS completion suffices (no barrier)
        __builtin_amdgcn_s_waitcnt(0xc07f);  // lgkmcnt(0)
        __builtin_amdgcn_sched_barrier(0);

        f16x8 pb0 = *(const f16x8*)(psrow + quad * 8);
        f16x8 pb1 = *(const f16x8*)(psrow + 32 + quad * 8);
#pragma unroll
        for (int nd = 0; nd < 4; nd++) {
            f16x8 v0 = *(const f16x8*)(VsB + boff[nd][0]);
            f16x8 v1 = *(const f16x8*)(VsB + boff[nd][1]);
            o[nd] = MFMA_F16(v0, pb0, o[nd]);
            o[nd] = MFMA_F16(v1, pb1, o[nd]);
        }
    }

    const int bw = wh >> 4, h = wh & 15;
    float inv = 1.f / l_l;
    f16* dst = AO + ((size_t)bw * 512 + ig) * 1024 + h * 64 + quad * 4;
#pragma unroll
    for (int nd = 0; nd < 4; nd++) {
        f16x4 ov;
#pragma unroll
        for (int r = 0; r < 4; r++) ov[r] = (f16)(o[nd][r] * inv);
        *(f16x4*)(dst + nd * 16) = ov;
    }
}

// ---------------------------------------------------------------- launch
extern "C" void kernel_launch(void* const* d_in, const int* in_sizes, int n_in,
                              void* d_out, int out_size, void* d_ws, size_t ws_size,
                              hipStream_t stream) {
    const float* seq   = (const float*)d_in[0];
    const float* wnorm = (const float*)d_in[1];
    const float* Wqkv  = (const float*)d_in[2];
    const float* Wout  = (const float*)d_in[3];
    const float* pm    = (const float*)d_in[4];
    float* out = (float*)d_out;
    char* ws = (char*)d_ws;

    f16* WqkvT = (f16*)(ws + 0);            // 3072x1024  = 6 MB
    f16* WoutT = (f16*)(ws + 6291456);      // 1024x1024  = 2 MB
    f16* X     = (f16*)(ws + 8388608);      // 16384x1024 = 32 MB
    f16* Qb    = (f16*)(ws + 41943040);     // 512x512x64 = 32 MB
    f16* AO    = (f16*)(ws + 75497472);     // 16384x1024 = 32 MB
    f16* Kb    = (f16*)(ws + 109051904);    // 512x576x64 = 36 MB
    f16* Vt    = (f16*)(ws + 146800640);    // 512x64x576 = 36 MB  (end 176 MB)

    k_transpose_cast<<<dim3(96, 32), 256, 0, stream>>>(Wqkv, WqkvT, 1024, 3072);
    k_transpose_cast<<<dim3(32, 32), 256, 0, stream>>>(Wout, WoutT, 1024, 1024);
    k_rmsnorm<<<16384, 256, 0, stream>>>(seq, wnorm, X);
    k_pmpad<<<512, 256, 0, stream>>>(pm, Kb, Vt);
    k_gemm_qkv<<<dim3(24, 128), 256, 0, stream>>>(X, WqkvT, Qb, Kb, Vt);
    k_attn<<<2048, 512, 0, stream>>>(Qb, Kb, Vt, AO);
    k_gemm_out<<<dim3(8, 128), 256, 0, stream>>>(AO, WoutT, out, 16384, 1024, 1024);
}